// Round 12
// baseline (22491.408 us; speedup 1.0000x reference)
//
#include <hip/hip_runtime.h>

// TruncatedHistoryAttn, round 18 = fused (round 16/17) with wa1/wa2 FORCED
// into AGPRs via v_accvgpr_write/read inline asm.
// Round-17 post-mortem: __launch_bounds__(512,1) did NOT lift the 128-VGPR
// allocator cap (VGPR_Count still 128, scratch still 77MB WRITE). The
// heuristic will not hold 192 float weights in arch VGPRs. Fix by
// construction (proven rounds 1-6 pattern): wa1+wa2 (128 floats) live in
// AGPRs (unified file headroom), wa3 (64) + ~50 working set in arch VGPRs
// ~ 114 <= 128 -> spill-free at the same 1 WG/CU occupancy round 15 had.
// Cost: +128 v_accvgpr_read per thread-step, overlapped with the fma stream.
// Design (unchanged): single kernel; per step THREE interleaved wave-local
// matvecs c_t=tilde@W3 (VGPR weights), a_t=H_t@W1, b_{t+2}=H_{t+2}@W2 (AGPR
// weights); H rows staged via LDS + lgkmcnt(0) (wave-local, no barrier);
// b 2-step pipeline (prologue computes B2 row 1); A/B2 never materialized;
// d_out gets only tilde rows (full overwrite). Exchange: tagged 8B agent
// words, early distributed publish (waves 1..4 at step start, j=4 at tail),
// wave-0-only poll with self-j4 register substitute, DPP cross-lane sums,
// 2 barriers/step, grid 256.

#define BB 32
#define SS 512
#define DD 512
#define NS 5

#define EXCH_U64_PER_B 128                           // 2 slots x 64 (40 used)
#define EXCH_BYTES ((size_t)BB * EXCH_U64_PER_B * 8) // 32 KB
#define WS_NEED    EXCH_BYTES

typedef __attribute__((ext_vector_type(4))) float f32x4;

// ---- DPP cross-lane sum (rocPRIM sequence); ctrl words are template consts.
template <int CTRL, int RMASK, int BMASK, bool BC>
__device__ __forceinline__ float dpp_term(float x) {
  return __uint_as_float((unsigned)__builtin_amdgcn_update_dpp(
      0, (int)__float_as_uint(x), CTRL, RMASK, BMASK, BC));
}
__device__ __forceinline__ float wave_sum64(float x) {
  x += dpp_term<0xB1, 0xF, 0xF, true>(x);   // quad_perm [1,0,3,2] (xor 1)
  x += dpp_term<0x4E, 0xF, 0xF, true>(x);   // quad_perm [2,3,0,1] (xor 2)
  x += dpp_term<0x141, 0xF, 0xF, true>(x);  // row_half_mirror     (xor 4)
  x += dpp_term<0x140, 0xF, 0xF, true>(x);  // row_mirror          (xor 8)
  x += dpp_term<0x142, 0xA, 0xF, false>(x); // row_bcast15 -> rows 1,3
  x += dpp_term<0x143, 0xC, 0xF, false>(x); // row_bcast31 -> rows 2,3
  return x;                                 // lane 63: sum of all 64
}
__device__ __forceinline__ float group8_sum(float x) {
  x += dpp_term<0xB1, 0xF, 0xF, true>(x);
  x += dpp_term<0x4E, 0xF, 0xF, true>(x);
  x += dpp_term<0x141, 0xF, 0xF, true>(x);
  return x;
}

#define AGPR_W(dst, src) \
  asm volatile("v_accvgpr_write_b32 %0, %1" : "=a"(dst) : "v"(src))
#define AGPR_R(dst, src) \
  asm volatile("v_accvgpr_read_b32 %0, %1" : "=v"(dst) : "a"(src))

// grid 256 = 8 WGs/batch; bid = g*32+b.
__global__ void __launch_bounds__(512) th_fused(
    const float* __restrict__ H, const float* __restrict__ v,
    const float* __restrict__ W1, const float* __restrict__ W2,
    const float* __restrict__ W3,
    float* __restrict__ Ob,            // d_out: tilde rows only
    unsigned long long* __restrict__ exch) {
  const int tid = threadIdx.x;
  const int b = blockIdx.x & 31;
  const int g = blockIdx.x >> 5;     // 0..7: cols [g*64, g*64+64)
  const int q = tid >> 6;            // wave id == k-segment 0..7
  const int ln = tid & 63;
  const int col = (g << 6) + ln;

  __shared__ float tlds[DD];         // tilde_t row
  __shared__ float hA[DD];           // H row t
  __shared__ float hB[DD];           // H row t+2
  __shared__ float pm0[DD];          // W3-matvec partials (c)
  __shared__ float pm1[DD];          // W1-matvec partials (a)
  __shared__ float pm2[DD];          // W2-matvec partials (b)
  __shared__ float wl[8];            // softmax weights broadcast

  // W3 col-slice in arch VGPRs; W1/W2 col-slices in AGPRs (forced).
  float wa3[64];
  float ag1[64], ag2[64];            // live in AGPRs via asm constraints
#pragma unroll
  for (int i = 0; i < 64; ++i) {
    const size_t off = (size_t)(q * 64 + i) * DD + col;
    wa3[i] = W3[off];
    float t1 = W1[off];
    float t2 = W2[off];
    AGPR_W(ag1[i], t1);
    AGPR_W(ag2[i], t2);
  }

  const float* Hb = H + (size_t)b * SS * DD;
  float* Op = Ob + (size_t)b * SS * DD;
  unsigned long long* eb = exch + (size_t)b * EXCH_U64_PER_B;

  // waves 0..4: replica rings over this WG's 64 cols (row s in slot s%5)
  float v_col = (q < NS) ? v[col] : 0.f;
  float aA[NS] = {0.f, 0.f, 0.f, 0.f, 0.f};
  float cC[NS] = {0.f, 0.f, 0.f, 0.f, 0.f};
  float tl[NS] = {0.f, 0.f, 0.f, 0.f, 0.f};
  float s4_prev = 0.f;               // wave 0: own j=4 score (all lanes)
  float h_cur = Hb[tid];             // H row 0
  float h_n1  = Hb[DD + tid];        // H row 1
  float btB = 0.f;                   // B2 row t+1 at own col (waves 0-4)

  if (tid < NS) wl[tid] = 0.2f;      // step-0 weights: exactly uniform

  // ---- prologue: btB = B2 row 1 = H_1 @ W2 (col-slice matvec, AGPR W2)
  {
    hB[tid] = h_n1;
    asm volatile("s_waitcnt lgkmcnt(0)" ::: "memory");
    float a0 = 0.f, a1 = 0.f, a2 = 0.f, a3 = 0.f;
    const f32x4* tv = (const f32x4*)&hB[q << 6];
#pragma unroll
    for (int i = 0; i < 16; ++i) {
      f32x4 t4 = tv[i];
      float y0, y1, y2, y3;
      AGPR_R(y0, ag2[4 * i + 0]);
      AGPR_R(y1, ag2[4 * i + 1]);
      AGPR_R(y2, ag2[4 * i + 2]);
      AGPR_R(y3, ag2[4 * i + 3]);
      a0 = fmaf(t4.x, y0, a0);
      a1 = fmaf(t4.y, y1, a1);
      a2 = fmaf(t4.z, y2, a2);
      a3 = fmaf(t4.w, y3, a3);
    }
    pm2[tid] = (a0 + a1) + (a2 + a3);
    __syncthreads();
    if (q < NS) {
      float bb = 0.f;
#pragma unroll
      for (int s = 0; s < 8; ++s) bb += pm2[s * 64 + ln];
      btB = bb;
    }
    __syncthreads();                 // pm2 free for step-0 reuse
  }

#pragma unroll 1
  for (int t5 = 0; t5 < 515; t5 += 5) {
#pragma unroll
    for (int p = 0; p < NS; ++p) {
      const int t = t5 + p;
      if (t < SS) {
        const bool pub = (t + 1 < SS);

        // ---- prefetch H row t+2 (staged into hB this step, b-matvec)
        float h_n2 = 0.f;
        if (t + 2 < SS) h_n2 = Hb[(size_t)(t + 2) * DD + tid];

        // ---- waves 1..4: EARLY publish of score j=q-1 for step t+1
        if (q >= 1 && q < NS && pub) {
          float aa = aA[(p + 1) % NS];
          aa = (q == 2) ? aA[(p + 2) % NS] : aa;
          aa = (q == 3) ? aA[(p + 3) % NS] : aa;
          aa = (q == 4) ? aA[(p + 4) % NS] : aa;
          float cc = cC[(p + 1) % NS];
          cc = (q == 2) ? cC[(p + 2) % NS] : cc;
          cc = (q == 3) ? cC[(p + 3) % NS] : cc;
          cc = (q == 4) ? cC[(p + 4) % NS] : cc;
          float x = aa + btB + cc;
          float e = __expf(2.0f * x);
          float s = (1.0f - 2.0f / (e + 1.0f)) * v_col;
          s = wave_sum64(s);                       // lane 63 = total
          if (ln == 63)
            __hip_atomic_store(&eb[(size_t)((t + 1) & 1) * 64 + (q - 1) * 8 + g],
                (unsigned long long)__float_as_uint(s) |
                    ((unsigned long long)(t + 2) << 32),
                __ATOMIC_RELAXED, __HIP_MEMORY_SCOPE_AGENT);
        }

        // ---- wave 0: poll tagged words (slot t&1, tag t+1) -> softmax -> wl
        if (q == 0 && t >= 1) {
          const unsigned long long* wsl = eb + (size_t)(t & 1) * 64;
          float pv = 0.f;
          if (ln < 40) {
            if (!((ln >> 3) == 4 && (ln & 7) == g)) {
              unsigned long long w;
              do {
                w = __hip_atomic_load(&wsl[ln], __ATOMIC_RELAXED,
                                      __HIP_MEMORY_SCOPE_AGENT);
              } while ((unsigned)(w >> 32) != (unsigned)(t + 1));
              pv = __uint_as_float((unsigned)w);
            } else {
              pv = s4_prev;
            }
          }
          pv = group8_sum(pv);             // each 8-group holds its j-total
          float sc0 = __shfl(pv, 0, 64);
          float sc1 = __shfl(pv, 8, 64);
          float sc2 = __shfl(pv, 16, 64);
          float sc3 = __shfl(pv, 24, 64);
          float sc4 = __shfl(pv, 32, 64);
          float mx = fmaxf(fmaxf(fmaxf(sc0, sc1), fmaxf(sc2, sc3)), sc4);
          float e0 = __expf(sc0 - mx), e1 = __expf(sc1 - mx);
          float e2 = __expf(sc2 - mx), e3 = __expf(sc3 - mx);
          float e4 = __expf(sc4 - mx);
          float inv = 1.0f / (e0 + e1 + e2 + e3 + e4);
          float wv = e0 * inv;
          wv = (ln == 1) ? e1 * inv : wv;
          wv = (ln == 2) ? e2 * inv : wv;
          wv = (ln == 3) ? e3 * inv : wv;
          wv = (ln == 4) ? e4 * inv : wv;
          if (ln < NS) wl[ln] = wv;
        }
        __syncthreads();                           // A: weights ready

        // ---- all threads: tilde row; stage tilde + H_t + H_{t+2} into LDS
        float w0 = wl[0], w1 = wl[1], w2 = wl[2], w3_ = wl[3], w4 = wl[4];
        float hh = w0 * tl[p];
        hh = fmaf(w1, tl[(p + 1) % NS], hh);
        hh = fmaf(w2, tl[(p + 2) % NS], hh);
        hh = fmaf(w3_, tl[(p + 3) % NS], hh);
        hh = fmaf(w4, tl[(p + 4) % NS], hh);
        float tld = h_cur + fmaxf(hh, 0.f);
        tl[p] = tld;
        tlds[tid] = tld;
        hA[tid] = h_cur;
        hB[tid] = h_n2;
        if (g == 0) Op[(size_t)t * DD + tid] = tld;  // output row t
        // wave-local: matvecs read ONLY this wave's own LDS segments
        asm volatile("s_waitcnt lgkmcnt(0)" ::: "memory");

        // ---- 3 interleaved matvecs: c_t (W3/VGPR), a_t (W1/AGPR),
        //      b_{t+2} (W2/AGPR)
        float c0 = 0.f, c1 = 0.f, c2 = 0.f, c3 = 0.f;
        float d0 = 0.f, d1 = 0.f, d2 = 0.f, d3 = 0.f;
        float f0 = 0.f, f1 = 0.f, f2 = 0.f, f3 = 0.f;
        const f32x4* tvT = (const f32x4*)&tlds[q << 6];
        const f32x4* tvA = (const f32x4*)&hA[q << 6];
        const f32x4* tvB = (const f32x4*)&hB[q << 6];
#pragma unroll
        for (int i = 0; i < 16; ++i) {
          f32x4 tt = tvT[i];
          f32x4 ta = tvA[i];
          f32x4 tb = tvB[i];
          c0 = fmaf(tt.x, wa3[4 * i + 0], c0);
          c1 = fmaf(tt.y, wa3[4 * i + 1], c1);
          c2 = fmaf(tt.z, wa3[4 * i + 2], c2);
          c3 = fmaf(tt.w, wa3[4 * i + 3], c3);
          float x0, x1, x2, x3;
          AGPR_R(x0, ag1[4 * i + 0]);
          AGPR_R(x1, ag1[4 * i + 1]);
          AGPR_R(x2, ag1[4 * i + 2]);
          AGPR_R(x3, ag1[4 * i + 3]);
          d0 = fmaf(ta.x, x0, d0);
          d1 = fmaf(ta.y, x1, d1);
          d2 = fmaf(ta.z, x2, d2);
          d3 = fmaf(ta.w, x3, d3);
          float y0, y1, y2, y3;
          AGPR_R(y0, ag2[4 * i + 0]);
          AGPR_R(y1, ag2[4 * i + 1]);
          AGPR_R(y2, ag2[4 * i + 2]);
          AGPR_R(y3, ag2[4 * i + 3]);
          f0 = fmaf(tb.x, y0, f0);
          f1 = fmaf(tb.y, y1, f1);
          f2 = fmaf(tb.z, y2, f2);
          f3 = fmaf(tb.w, y3, f3);
        }
        pm0[tid] = (c0 + c1) + (c2 + c3);
        pm1[tid] = (d0 + d1) + (d2 + d3);
        pm2[tid] = (f0 + f1) + (f2 + f3);
        __syncthreads();                           // C: pm ready

        // ---- waves 0..4: reduce c_t, a_t, b_{t+2}; wave 0: j=4 publish
        if (q < NS) {
          float c = 0.f, a = 0.f, bb = 0.f;
#pragma unroll
          for (int s = 0; s < 8; ++s) {
            c  += pm0[s * 64 + ln];
            a  += pm1[s * 64 + ln];
            bb += pm2[s * 64 + ln];
          }
          aA[p] = a;                               // A row t -> slot t%5
          cC[p] = c;                               // c row t -> slot t%5
          if (q == 0 && pub) {
            float x = a + btB + c;                 // row t, bt = row t+1
            float e = __expf(2.0f * x);
            float s4 = (1.0f - 2.0f / (e + 1.0f)) * v_col;
            s4 = wave_sum64(s4);                   // lane 63 = total
            if (ln == 63)
              __hip_atomic_store(&eb[(size_t)((t + 1) & 1) * 64 + 32 + g],
                  (unsigned long long)__float_as_uint(s4) |
                      ((unsigned long long)(t + 2) << 32),
                  __ATOMIC_RELAXED, __HIP_MEMORY_SCOPE_AGENT);
            s4_prev = __shfl(s4, 63, 64);          // off-critical broadcast
          }
          btB = bb;                                // B2 row t+2 for step t+1
        }
        h_cur = h_n1;
        h_n1 = h_n2;
      }
    }
  }
}

extern "C" void kernel_launch(void* const* d_in, const int* in_sizes, int n_in,
                              void* d_out, int out_size, void* d_ws, size_t ws_size,
                              hipStream_t stream) {
  const float* H  = (const float*)d_in[0];
  const float* v  = (const float*)d_in[1];
  const float* W1 = (const float*)d_in[2];
  const float* W2 = (const float*)d_in[3];
  const float* W3 = (const float*)d_in[4];
  float* out = (float*)d_out;

  if (ws_size < WS_NEED) return;

  unsigned long long* exch = (unsigned long long*)d_ws;

  (void)hipMemsetAsync(exch, 0, EXCH_BYTES, stream);
  hipLaunchKernelGGL(th_fused, dim3(BB * 8), dim3(512), 0, stream,
                     H, v, W1, W2, W3, out, exch);
}

// Round 14
// 2878.592 us; speedup vs baseline: 7.8133x; 7.8133x over previous
//
#include <hip/hip_runtime.h>

// TruncatedHistoryAttn, round 20 = round 19 with the stray racy Op write
// removed (round-19 post-mortem: a leftover duplicate line made g!=0 WGs
// read-modify-write Op[t], racing with g==0's tilde store -> absmax 31).
// Design (unchanged from round 19):
//  - phase1 computes A = H@W1 alone (half FLOPs, half stores).
//  - phase2 adds ONE wave-local 64-AGPR matvec: b_{t+2} = H_{t+2}@W2
//    (rounds 1-6 proven envelope: 64 AGPR weights + ~104 VGPRs, spill-free).
//    Prologue computes B2 row 1; scores at step t use btB = B2 row t+1;
//    tail sets btB = row t+2. B2 never touches HBM.
//  - d_out receives ONLY tilde rows (g==0, row t at step t).
// Everything else = round 15 (best verified 1131us): tagged 8B agent words,
// early distributed publish (waves 1..4 at step start, j=4 at tail),
// wave-0-only poll with self-j4 register substitute, DPP cross-lane sums,
// wave-local ds_read_b128 c-matvec, 2 barriers/step, grid 256.

#define BB 32
#define SS 512
#define DD 512
#define NS 5

#define A_ELEMS    ((size_t)BB * SS * DD)            // 32 MB (A only)
#define EXCH_U64_PER_B 128                           // 2 slots x 64 (40 used)
#define EXCH_OFF   (A_ELEMS * 4)
#define EXCH_BYTES ((size_t)BB * EXCH_U64_PER_B * 8) // 32 KB
#define WS_NEED    (EXCH_OFF + EXCH_BYTES)

typedef __attribute__((ext_vector_type(4))) float f32x4;

// ---- DPP cross-lane sum (rocPRIM sequence); ctrl words are template consts.
template <int CTRL, int RMASK, int BMASK, bool BC>
__device__ __forceinline__ float dpp_term(float x) {
  return __uint_as_float((unsigned)__builtin_amdgcn_update_dpp(
      0, (int)__float_as_uint(x), CTRL, RMASK, BMASK, BC));
}
__device__ __forceinline__ float wave_sum64(float x) {
  x += dpp_term<0xB1, 0xF, 0xF, true>(x);   // quad_perm [1,0,3,2] (xor 1)
  x += dpp_term<0x4E, 0xF, 0xF, true>(x);   // quad_perm [2,3,0,1] (xor 2)
  x += dpp_term<0x141, 0xF, 0xF, true>(x);  // row_half_mirror     (xor 4)
  x += dpp_term<0x140, 0xF, 0xF, true>(x);  // row_mirror          (xor 8)
  x += dpp_term<0x142, 0xA, 0xF, false>(x); // row_bcast15 -> rows 1,3
  x += dpp_term<0x143, 0xC, 0xF, false>(x); // row_bcast31 -> rows 2,3
  return x;                                 // lane 63: sum of all 64
}
__device__ __forceinline__ float group8_sum(float x) {
  x += dpp_term<0xB1, 0xF, 0xF, true>(x);
  x += dpp_term<0x4E, 0xF, 0xF, true>(x);
  x += dpp_term<0x141, 0xF, 0xF, true>(x);
  return x;
}

#define AGPR_W(dst, src) \
  asm volatile("v_accvgpr_write_b32 %0, %1" : "=a"(dst) : "v"(src))
#define AGPR_R(dst, src) \
  asm volatile("v_accvgpr_read_b32 %0, %1" : "=v"(dst) : "a"(src))

// ---------------- Phase 1: A = H@W1 (fp32, single output) ----------------
__global__ void __launch_bounds__(256) th_phase1(
    const float* __restrict__ H, const float* __restrict__ W1,
    float* __restrict__ A) {
  const int tid = threadIdx.x;
  const int mt = blockIdx.x >> 3;
  const int nt = blockIdx.x & 7;
  const int m0 = mt << 6, n0 = nt << 6;
  __shared__ float Ht[64][20];
  __shared__ float Wt1[16][64];
  const int tx = tid & 15, ty = tid >> 4;
  const int sr = tid >> 2, sk = (tid & 3) << 2;
  const int wr = tid >> 4, wn = (tid & 15) << 2;
  float a1[4][4] = {{0.f}};

  for (int k0 = 0; k0 < DD; k0 += 16) {
    float4 hv  = *(const float4*)&H[(size_t)(m0 + sr) * DD + k0 + sk];
    float4 w1v = *(const float4*)&W1[(size_t)(k0 + wr) * DD + n0 + wn];
    *(float4*)&Ht[sr][sk]  = hv;
    *(float4*)&Wt1[wr][wn] = w1v;
    __syncthreads();
#pragma unroll
    for (int kq = 0; kq < 16; kq += 4) {
      float hs[4][4];
#pragma unroll
      for (int i = 0; i < 4; ++i) {
        float4 h4 = *(const float4*)&Ht[ty * 4 + i][kq];
        hs[i][0] = h4.x; hs[i][1] = h4.y; hs[i][2] = h4.z; hs[i][3] = h4.w;
      }
#pragma unroll
      for (int kk = 0; kk < 4; ++kk) {
        float4 w1f = *(const float4*)&Wt1[kq + kk][tx * 4];
#pragma unroll
        for (int i = 0; i < 4; ++i) {
          float h = hs[i][kk];
          a1[i][0] = fmaf(h, w1f.x, a1[i][0]);
          a1[i][1] = fmaf(h, w1f.y, a1[i][1]);
          a1[i][2] = fmaf(h, w1f.z, a1[i][2]);
          a1[i][3] = fmaf(h, w1f.w, a1[i][3]);
        }
      }
    }
    __syncthreads();
  }
#pragma unroll
  for (int i = 0; i < 4; ++i) {
    float4 o1 = make_float4(a1[i][0], a1[i][1], a1[i][2], a1[i][3]);
    size_t off = (size_t)(m0 + ty * 4 + i) * DD + n0 + tx * 4;
    *(float4*)&A[off] = o1;
  }
}

// ---------------- Phase 2: the recurrence (+fused W2 matvec) ----------------
// grid 256 = 8 WGs/batch.
__global__ void __launch_bounds__(512) th_phase2(
    const float* __restrict__ H, const float* __restrict__ v,
    const float* __restrict__ W2, const float* __restrict__ W3,
    const float* __restrict__ A,
    float* __restrict__ Ob,            // d_out: tilde rows only
    unsigned long long* __restrict__ exch) {
  const int tid = threadIdx.x;
  const int b = blockIdx.x & 31;
  const int g = blockIdx.x >> 5;     // 0..7: cols [g*64, g*64+64)
  const int q = tid >> 6;            // wave id == k-segment 0..7
  const int ln = tid & 63;
  const int col = (g << 6) + ln;

  __shared__ float tlds[DD];         // tilde_t row
  __shared__ float hB[DD];           // H row t+2 (b-matvec input)
  __shared__ float pm[DD];           // c-matvec partials
  __shared__ float pm2[DD];          // b-matvec partials
  __shared__ float wl[8];            // softmax weights broadcast

  // W3 col-slice in VGPRs; W2 col-slice in AGPRs (rounds-1..6 envelope).
  float wa[64];
  float ag2[64];
#pragma unroll
  for (int i = 0; i < 64; ++i) {
    const size_t off = (size_t)(q * 64 + i) * DD + col;
    wa[i] = W3[off];
    float t2 = W2[off];
    AGPR_W(ag2[i], t2);
  }

  const float* Hb = H + (size_t)b * SS * DD;
  const float* Ab = A + (size_t)b * SS * DD;
  float* Op = Ob + (size_t)b * SS * DD;
  unsigned long long* eb = exch + (size_t)b * EXCH_U64_PER_B;

  // waves 0..4: replica rings over this WG's 64 cols (row s in slot s%5)
  float v_col = (q < NS) ? v[col] : 0.f;
  float aA[NS] = {0.f, 0.f, 0.f, 0.f, 0.f};
  float cC[NS] = {0.f, 0.f, 0.f, 0.f, 0.f};
  float tl[NS] = {0.f, 0.f, 0.f, 0.f, 0.f};
  float s4_prev = 0.f;               // wave 0: own j=4 score (all lanes)
  float h_cur = Hb[tid];             // H row 0
  float h_n1  = Hb[DD + tid];        // H row 1
  float btB = 0.f;                   // B2 row t+1 at own col (waves 0-4)

  if (tid < NS) wl[tid] = 0.2f;      // step-0 weights: exactly uniform

  // ---- prologue: btB = B2 row 1 = H_1 @ W2 (wave-local AGPR matvec)
  {
    hB[tid] = h_n1;
    asm volatile("s_waitcnt lgkmcnt(0)" ::: "memory");
    float a0 = 0.f, a1 = 0.f, a2 = 0.f, a3 = 0.f;
    const f32x4* tv = (const f32x4*)&hB[q << 6];
#pragma unroll
    for (int i = 0; i < 16; ++i) {
      f32x4 t4 = tv[i];
      float y0, y1, y2, y3;
      AGPR_R(y0, ag2[4 * i + 0]);
      AGPR_R(y1, ag2[4 * i + 1]);
      AGPR_R(y2, ag2[4 * i + 2]);
      AGPR_R(y3, ag2[4 * i + 3]);
      a0 = fmaf(t4.x, y0, a0);
      a1 = fmaf(t4.y, y1, a1);
      a2 = fmaf(t4.z, y2, a2);
      a3 = fmaf(t4.w, y3, a3);
    }
    pm2[tid] = (a0 + a1) + (a2 + a3);
    __syncthreads();
    if (q < NS) {
      float bb = 0.f;
#pragma unroll
      for (int s = 0; s < 8; ++s) bb += pm2[s * 64 + ln];
      btB = bb;
    }
    __syncthreads();                 // pm2 free for step-0 reuse
  }

#pragma unroll 1
  for (int t5 = 0; t5 < 515; t5 += 5) {
#pragma unroll
    for (int p = 0; p < NS; ++p) {
      const int t = t5 + p;
      if (t < SS) {
        const bool pub = (t + 1 < SS);

        // ---- prefetches: A row t (waves 0-4), H row t+2 (all)
        float aN_v = 0.f;
        if (q < NS) aN_v = Ab[(size_t)t * DD + col];
        float h_n2 = 0.f;
        if (t + 2 < SS) h_n2 = Hb[(size_t)(t + 2) * DD + tid];

        // ---- waves 1..4: EARLY publish of score j=q-1 for step t+1
        if (q >= 1 && q < NS && pub) {
          float aa = aA[(p + 1) % NS];
          aa = (q == 2) ? aA[(p + 2) % NS] : aa;
          aa = (q == 3) ? aA[(p + 3) % NS] : aa;
          aa = (q == 4) ? aA[(p + 4) % NS] : aa;
          float cc = cC[(p + 1) % NS];
          cc = (q == 2) ? cC[(p + 2) % NS] : cc;
          cc = (q == 3) ? cC[(p + 3) % NS] : cc;
          cc = (q == 4) ? cC[(p + 4) % NS] : cc;
          float x = aa + btB + cc;
          float e = __expf(2.0f * x);
          float s = (1.0f - 2.0f / (e + 1.0f)) * v_col;
          s = wave_sum64(s);                       // lane 63 = total
          if (ln == 63)
            __hip_atomic_store(&eb[(size_t)((t + 1) & 1) * 64 + (q - 1) * 8 + g],
                (unsigned long long)__float_as_uint(s) |
                    ((unsigned long long)(t + 2) << 32),
                __ATOMIC_RELAXED, __HIP_MEMORY_SCOPE_AGENT);
        }

        // ---- wave 0: poll tagged words (slot t&1, tag t+1) -> softmax -> wl
        if (q == 0 && t >= 1) {
          const unsigned long long* wsl = eb + (size_t)(t & 1) * 64;
          float pv = 0.f;
          if (ln < 40) {
            if (!((ln >> 3) == 4 && (ln & 7) == g)) {
              unsigned long long w;
              do {
                w = __hip_atomic_load(&wsl[ln], __ATOMIC_RELAXED,
                                      __HIP_MEMORY_SCOPE_AGENT);
              } while ((unsigned)(w >> 32) != (unsigned)(t + 1));
              pv = __uint_as_float((unsigned)w);
            } else {
              pv = s4_prev;
            }
          }
          pv = group8_sum(pv);             // each 8-group holds its j-total
          float sc0 = __shfl(pv, 0, 64);
          float sc1 = __shfl(pv, 8, 64);
          float sc2 = __shfl(pv, 16, 64);
          float sc3 = __shfl(pv, 24, 64);
          float sc4 = __shfl(pv, 32, 64);
          float mx = fmaxf(fmaxf(fmaxf(sc0, sc1), fmaxf(sc2, sc3)), sc4);
          float e0 = __expf(sc0 - mx), e1 = __expf(sc1 - mx);
          float e2 = __expf(sc2 - mx), e3 = __expf(sc3 - mx);
          float e4 = __expf(sc4 - mx);
          float inv = 1.0f / (e0 + e1 + e2 + e3 + e4);
          float wv = e0 * inv;
          wv = (ln == 1) ? e1 * inv : wv;
          wv = (ln == 2) ? e2 * inv : wv;
          wv = (ln == 3) ? e3 * inv : wv;
          wv = (ln == 4) ? e4 * inv : wv;
          if (ln < NS) wl[ln] = wv;
        }
        __syncthreads();                           // A: weights ready

        // ---- all threads: tilde row; stage tilde + H_{t+2} into LDS
        float w0 = wl[0], w1 = wl[1], w2 = wl[2], w3_ = wl[3], w4 = wl[4];
        float hh = w0 * tl[p];
        hh = fmaf(w1, tl[(p + 1) % NS], hh);
        hh = fmaf(w2, tl[(p + 2) % NS], hh);
        hh = fmaf(w3_, tl[(p + 3) % NS], hh);
        hh = fmaf(w4, tl[(p + 4) % NS], hh);
        float tld = h_cur + fmaxf(hh, 0.f);
        tl[p] = tld;
        tlds[tid] = tld;
        hB[tid] = h_n2;
        if (g == 0) Op[(size_t)t * DD + tid] = tld;  // output row t
        // wave-local: matvecs read ONLY this wave's own LDS segments
        asm volatile("s_waitcnt lgkmcnt(0)" ::: "memory");

        // ---- 2 interleaved matvecs: c_t (W3/VGPR), b_{t+2} (W2/AGPR)
        float a0 = 0.f, a1 = 0.f, a2 = 0.f, a3 = 0.f;
        float f0 = 0.f, f1 = 0.f, f2 = 0.f, f3 = 0.f;
        const f32x4* tvT = (const f32x4*)&tlds[q << 6];
        const f32x4* tvB = (const f32x4*)&hB[q << 6];
#pragma unroll
        for (int i = 0; i < 16; ++i) {
          f32x4 tt = tvT[i];
          f32x4 tb = tvB[i];
          a0 = fmaf(tt.x, wa[4 * i + 0], a0);
          a1 = fmaf(tt.y, wa[4 * i + 1], a1);
          a2 = fmaf(tt.z, wa[4 * i + 2], a2);
          a3 = fmaf(tt.w, wa[4 * i + 3], a3);
          float y0, y1, y2, y3;
          AGPR_R(y0, ag2[4 * i + 0]);
          AGPR_R(y1, ag2[4 * i + 1]);
          AGPR_R(y2, ag2[4 * i + 2]);
          AGPR_R(y3, ag2[4 * i + 3]);
          f0 = fmaf(tb.x, y0, f0);
          f1 = fmaf(tb.y, y1, f1);
          f2 = fmaf(tb.z, y2, f2);
          f3 = fmaf(tb.w, y3, f3);
        }
        pm[tid]  = (a0 + a1) + (a2 + a3);
        pm2[tid] = (f0 + f1) + (f2 + f3);
        __syncthreads();                           // C: pm ready

        // ---- waves 0..4: reduce c_t and b_{t+2}; wave 0: j=4 publish
        if (q < NS) {
          float c = 0.f, bb = 0.f;
#pragma unroll
          for (int s = 0; s < 8; ++s) {
            c  += pm[s * 64 + ln];
            bb += pm2[s * 64 + ln];
          }
          aA[p] = aN_v;                            // A row t -> slot t%5
          cC[p] = c;                               // c row t -> slot t%5
          if (q == 0 && pub) {
            float x = aN_v + btB + c;              // row t, bt = row t+1
            float e = __expf(2.0f * x);
            float s4 = (1.0f - 2.0f / (e + 1.0f)) * v_col;
            s4 = wave_sum64(s4);                   // lane 63 = total
            if (ln == 63)
              __hip_atomic_store(&eb[(size_t)((t + 1) & 1) * 64 + 32 + g],
                  (unsigned long long)__float_as_uint(s4) |
                      ((unsigned long long)(t + 2) << 32),
                  __ATOMIC_RELAXED, __HIP_MEMORY_SCOPE_AGENT);
            s4_prev = __shfl(s4, 63, 64);          // off-critical broadcast
          }
          btB = bb;                                // B2 row t+2 for step t+1
        }
        h_cur = h_n1;
        h_n1 = h_n2;
      }
    }
  }
}

extern "C" void kernel_launch(void* const* d_in, const int* in_sizes, int n_in,
                              void* d_out, int out_size, void* d_ws, size_t ws_size,
                              hipStream_t stream) {
  const float* H  = (const float*)d_in[0];
  const float* v  = (const float*)d_in[1];
  const float* W1 = (const float*)d_in[2];
  const float* W2 = (const float*)d_in[3];
  const float* W3 = (const float*)d_in[4];
  float* out = (float*)d_out;

  if (ws_size < WS_NEED) return;

  float* A = (float*)d_ws;
  unsigned long long* exch = (unsigned long long*)((char*)d_ws + EXCH_OFF);

  (void)hipMemsetAsync(exch, 0, EXCH_BYTES, stream);
  hipLaunchKernelGGL(th_phase1, dim3(256 * 8), dim3(256), 0, stream,
                     H, W1, A);
  hipLaunchKernelGGL(th_phase2, dim3(BB * 8), dim3(512), 0, stream,
                     H, v, W2, W3, A, out, exch);
}

// Round 15
// 1110.554 us; speedup vs baseline: 20.2524x; 2.5920x over previous
//
#include <hip/hip_runtime.h>

// TruncatedHistoryAttn, round 21 = round 15 VERBATIM (best verified: 1131us
// total, phase2 857us, VGPR 84, no scratch).
// Round-20 post-mortem: the half-fusion (64 AGPR W2 + 64 VGPR W3) also
// spilled (VGPR=128 cap, WRITE 109MB, 2788us) - this kernel's live state
// (DPP temps, h pipeline, replica rings) exceeds rounds-1..6's envelope.
// Four consecutive register-capacity failures (r16 default, r17 bounds(512,1),
// r18 forced-AGPR 128w, r20 forced-AGPR 64w): fusion direction is dead.
// Remaining structure: phase2's ~4000cy/step is ~50-60% exposed agent-scope
// LLC publish->detect round trip (the only coherent channel across sibling
// WGs; sc0/L2 shortcut disproven r13; interleave hiding loses to barrier
// coupling r10/r12). Local chain already minimized: DPP sums (r15), early
// distributed publish (r11), tagged single-word exchange (r9), wave-local
// matvec (r9). Sync-latency floor for the 8-WG decomposition.
// Phase 1: fp32 tiled GEMM  A = H@W1 (-> ws), B2 = H@W2 (-> d_out).
// Phase 2: tagged 8B agent words (store IS the publication), waves 1..4
// publish j=0..3 at step start / wave 0 publishes j=4 at tail, wave-0-only
// poll with self-j4 register substitute, DPP cross-lane sums, wave-local
// ds_read_b128 matvec, 2 barriers/step, grid 256.

#define BB 32
#define SS 512
#define DD 512
#define NS 5

#define A_ELEMS    ((size_t)BB * SS * DD)            // 32 MB
#define EXCH_U64_PER_B 128                           // 2 slots x 64 (40 used)
#define EXCH_OFF   (A_ELEMS * 4)
#define EXCH_BYTES ((size_t)BB * EXCH_U64_PER_B * 8) // 32 KB
#define WS_NEED    (EXCH_OFF + EXCH_BYTES)

typedef __attribute__((ext_vector_type(4))) float f32x4;

// ---- DPP cross-lane sum (rocPRIM sequence); ctrl words are template consts.
template <int CTRL, int RMASK, int BMASK, bool BC>
__device__ __forceinline__ float dpp_term(float x) {
  return __uint_as_float((unsigned)__builtin_amdgcn_update_dpp(
      0, (int)__float_as_uint(x), CTRL, RMASK, BMASK, BC));
}
__device__ __forceinline__ float wave_sum64(float x) {
  x += dpp_term<0xB1, 0xF, 0xF, true>(x);   // quad_perm [1,0,3,2] (xor 1)
  x += dpp_term<0x4E, 0xF, 0xF, true>(x);   // quad_perm [2,3,0,1] (xor 2)
  x += dpp_term<0x141, 0xF, 0xF, true>(x);  // row_half_mirror     (xor 4)
  x += dpp_term<0x140, 0xF, 0xF, true>(x);  // row_mirror          (xor 8)
  x += dpp_term<0x142, 0xA, 0xF, false>(x); // row_bcast15 -> rows 1,3
  x += dpp_term<0x143, 0xC, 0xF, false>(x); // row_bcast31 -> rows 2,3
  return x;                                 // lane 63: sum of all 64
}
// sum within each 8-lane group (every lane ends with its group's sum)
__device__ __forceinline__ float group8_sum(float x) {
  x += dpp_term<0xB1, 0xF, 0xF, true>(x);
  x += dpp_term<0x4E, 0xF, 0xF, true>(x);
  x += dpp_term<0x141, 0xF, 0xF, true>(x);
  return x;
}

// ---------------- Phase 1: A = H@W1, B2 = H@W2 (fp32) ----------------
__global__ void __launch_bounds__(256) th_phase1(
    const float* __restrict__ H, const float* __restrict__ W1,
    const float* __restrict__ W2, float* __restrict__ A, float* __restrict__ B2) {
  const int tid = threadIdx.x;
  const int mt = blockIdx.x >> 3;
  const int nt = blockIdx.x & 7;
  const int m0 = mt << 6, n0 = nt << 6;
  __shared__ float Ht[64][20];
  __shared__ float Wt1[16][64];
  __shared__ float Wt2[16][64];
  const int tx = tid & 15, ty = tid >> 4;
  const int sr = tid >> 2, sk = (tid & 3) << 2;
  const int wr = tid >> 4, wn = (tid & 15) << 2;
  float a1[4][4] = {{0.f}}, a2[4][4] = {{0.f}};

  for (int k0 = 0; k0 < DD; k0 += 16) {
    float4 hv  = *(const float4*)&H[(size_t)(m0 + sr) * DD + k0 + sk];
    float4 w1v = *(const float4*)&W1[(size_t)(k0 + wr) * DD + n0 + wn];
    float4 w2v = *(const float4*)&W2[(size_t)(k0 + wr) * DD + n0 + wn];
    *(float4*)&Ht[sr][sk]  = hv;
    *(float4*)&Wt1[wr][wn] = w1v;
    *(float4*)&Wt2[wr][wn] = w2v;
    __syncthreads();
#pragma unroll
    for (int kq = 0; kq < 16; kq += 4) {
      float hs[4][4];
#pragma unroll
      for (int i = 0; i < 4; ++i) {
        float4 h4 = *(const float4*)&Ht[ty * 4 + i][kq];
        hs[i][0] = h4.x; hs[i][1] = h4.y; hs[i][2] = h4.z; hs[i][3] = h4.w;
      }
#pragma unroll
      for (int kk = 0; kk < 4; ++kk) {
        float4 w1f = *(const float4*)&Wt1[kq + kk][tx * 4];
        float4 w2f = *(const float4*)&Wt2[kq + kk][tx * 4];
#pragma unroll
        for (int i = 0; i < 4; ++i) {
          float h = hs[i][kk];
          a1[i][0] = fmaf(h, w1f.x, a1[i][0]);
          a1[i][1] = fmaf(h, w1f.y, a1[i][1]);
          a1[i][2] = fmaf(h, w1f.z, a1[i][2]);
          a1[i][3] = fmaf(h, w1f.w, a1[i][3]);
          a2[i][0] = fmaf(h, w2f.x, a2[i][0]);
          a2[i][1] = fmaf(h, w2f.y, a2[i][1]);
          a2[i][2] = fmaf(h, w2f.z, a2[i][2]);
          a2[i][3] = fmaf(h, w2f.w, a2[i][3]);
        }
      }
    }
    __syncthreads();
  }
#pragma unroll
  for (int i = 0; i < 4; ++i) {
    float4 o1 = make_float4(a1[i][0], a1[i][1], a1[i][2], a1[i][3]);
    float4 o2 = make_float4(a2[i][0], a2[i][1], a2[i][2], a2[i][3]);
    size_t off = (size_t)(m0 + ty * 4 + i) * DD + n0 + tx * 4;
    *(float4*)&A[off]  = o1;
    *(float4*)&B2[off] = o2;
  }
}

// ---------------- Phase 2: the recurrence ----------------
// grid 256 = 8 WGs/batch.
__global__ void __launch_bounds__(512) th_phase2(
    const float* __restrict__ H, const float* __restrict__ v,
    const float* __restrict__ W3, const float* __restrict__ A,
    float* __restrict__ Ob,  // d_out: holds B2, overwritten with tilde rows
    unsigned long long* __restrict__ exch) {
  const int tid = threadIdx.x;
  const int b = blockIdx.x & 31;
  const int g = blockIdx.x >> 5;     // 0..7: cols [g*64, g*64+64)
  const int q = tid >> 6;            // wave id == k-segment 0..7
  const int ln = tid & 63;
  const int col = (g << 6) + ln;

  __shared__ float tlds[DD];         // tilde_t row
  __shared__ float pm[DD];           // matvec k-segment partials
  __shared__ float wl[8];            // softmax weights broadcast

  // W3 slice in plain VGPRs: wa[i] = W3[q*64+i][col]
  float wa[64];
#pragma unroll
  for (int i = 0; i < 64; ++i)
    wa[i] = W3[(size_t)(q * 64 + i) * DD + col];

  const float* Hb = H + (size_t)b * SS * DD;
  const float* Ab = A + (size_t)b * SS * DD;
  float* Op = Ob + (size_t)b * SS * DD;
  unsigned long long* eb = exch + (size_t)b * EXCH_U64_PER_B;

  // waves 0..4: replica rings over this WG's 64 cols (row s in slot s%5)
  float v_col = (q < NS) ? v[col] : 0.f;
  float aA[NS] = {0.f, 0.f, 0.f, 0.f, 0.f};
  float cC[NS] = {0.f, 0.f, 0.f, 0.f, 0.f};
  float tl[NS] = {0.f, 0.f, 0.f, 0.f, 0.f};
  float s4_prev = 0.f;               // wave 0: own j=4 score (all lanes)
  float h_cur = Hb[tid];
  float btB = (q < NS) ? Op[DD + col] : 0.f;  // B2 row t+1 (init: row 1)

  if (tid < NS) wl[tid] = 0.2f;      // step-0 weights: exactly uniform

#pragma unroll 1
  for (int t5 = 0; t5 < 515; t5 += 5) {
#pragma unroll
    for (int p = 0; p < NS; ++p) {
      const int t = t5 + p;
      if (t < SS) {
        const bool pub = (t + 1 < SS);

        // ---- prefetches
        float aN_v = 0.f, bt2 = 0.f;
        if (q < NS) {
          aN_v = Ab[(size_t)t * DD + col];                  // A row t
          if (t + 2 < SS) bt2 = Op[(size_t)(t + 2) * DD + col];  // B2 row t+2
        }
        float h_nxt = 0.f;
        if (pub) h_nxt = Hb[(size_t)(t + 1) * DD + tid];

        // ---- waves 1..4: EARLY publish of score j=q-1 for step t+1
        if (q >= 1 && q < NS && pub) {
          float aa = aA[(p + 1) % NS];
          aa = (q == 2) ? aA[(p + 2) % NS] : aa;
          aa = (q == 3) ? aA[(p + 3) % NS] : aa;
          aa = (q == 4) ? aA[(p + 4) % NS] : aa;
          float cc = cC[(p + 1) % NS];
          cc = (q == 2) ? cC[(p + 2) % NS] : cc;
          cc = (q == 3) ? cC[(p + 3) % NS] : cc;
          cc = (q == 4) ? cC[(p + 4) % NS] : cc;
          float x = aa + btB + cc;
          float e = __expf(2.0f * x);
          float s = (1.0f - 2.0f / (e + 1.0f)) * v_col;
          s = wave_sum64(s);                       // lane 63 = total
          if (ln == 63)
            __hip_atomic_store(&eb[(size_t)((t + 1) & 1) * 64 + (q - 1) * 8 + g],
                (unsigned long long)__float_as_uint(s) |
                    ((unsigned long long)(t + 2) << 32),
                __ATOMIC_RELAXED, __HIP_MEMORY_SCOPE_AGENT);
        }

        // ---- wave 0: poll tagged words (slot t&1, tag t+1) -> softmax -> wl
        if (q == 0 && t >= 1) {
          const unsigned long long* wsl = eb + (size_t)(t & 1) * 64;
          float pv = 0.f;
          if (ln < 40) {
            if (!((ln >> 3) == 4 && (ln & 7) == g)) {
              unsigned long long w;
              do {
                w = __hip_atomic_load(&wsl[ln], __ATOMIC_RELAXED,
                                      __HIP_MEMORY_SCOPE_AGENT);
              } while ((unsigned)(w >> 32) != (unsigned)(t + 1));
              pv = __uint_as_float((unsigned)w);
            } else {
              pv = s4_prev;
            }
          }
          pv = group8_sum(pv);             // each 8-group holds its j-total
          float sc0 = __shfl(pv, 0, 64);
          float sc1 = __shfl(pv, 8, 64);
          float sc2 = __shfl(pv, 16, 64);
          float sc3 = __shfl(pv, 24, 64);
          float sc4 = __shfl(pv, 32, 64);
          float mx = fmaxf(fmaxf(fmaxf(sc0, sc1), fmaxf(sc2, sc3)), sc4);
          float e0 = __expf(sc0 - mx), e1 = __expf(sc1 - mx);
          float e2 = __expf(sc2 - mx), e3 = __expf(sc3 - mx);
          float e4 = __expf(sc4 - mx);
          float inv = 1.0f / (e0 + e1 + e2 + e3 + e4);
          float wv = e0 * inv;
          wv = (ln == 1) ? e1 * inv : wv;
          wv = (ln == 2) ? e2 * inv : wv;
          wv = (ln == 3) ? e3 * inv : wv;
          wv = (ln == 4) ? e4 * inv : wv;
          if (ln < NS) wl[ln] = wv;
        }
        __syncthreads();                           // A: weights ready

        // ---- all threads: tilde row (registers + 5 broadcast LDS reads)
        float w0 = wl[0], w1 = wl[1], w2 = wl[2], w3_ = wl[3], w4 = wl[4];
        float hh = w0 * tl[p];
        hh = fmaf(w1, tl[(p + 1) % NS], hh);
        hh = fmaf(w2, tl[(p + 2) % NS], hh);
        hh = fmaf(w3_, tl[(p + 3) % NS], hh);
        hh = fmaf(w4, tl[(p + 4) % NS], hh);
        float tld = h_cur + fmaxf(hh, 0.f);
        tl[p] = tld;
        tlds[tid] = tld;
        if (g == 0) Op[(size_t)t * DD + tid] = tld;  // row t dead (poll passed)
        // wave-local: matvec reads ONLY this wave's own tlds segment
        asm volatile("s_waitcnt lgkmcnt(0)" ::: "memory");

        // ---- matvec: own 64 cols, k in [q*64, q*64+64), wave-uniform reads
        float a0 = 0.f, a1 = 0.f, a2 = 0.f, a3 = 0.f;
        const f32x4* tv = (const f32x4*)&tlds[q << 6];
#pragma unroll
        for (int i = 0; i < 16; ++i) {
          f32x4 t4 = tv[i];
          a0 = fmaf(t4.x, wa[4 * i + 0], a0);
          a1 = fmaf(t4.y, wa[4 * i + 1], a1);
          a2 = fmaf(t4.z, wa[4 * i + 2], a2);
          a3 = fmaf(t4.w, wa[4 * i + 3], a3);
        }
        pm[tid] = (a0 + a1) + (a2 + a3);
        __syncthreads();                           // C: pm ready

        // ---- waves 0..4: k-reduce + ring update; wave 0: score j=4, publish
        if (q < NS) {
          float c = 0.f;
#pragma unroll
          for (int s = 0; s < 8; ++s) c += pm[s * 64 + ln];
          aA[p] = aN_v;                            // A row t -> slot t%5
          cC[p] = c;                               // c row t -> slot t%5
          if (q == 0 && pub) {
            float x = aN_v + btB + c;              // row t, bt = row t+1
            float e = __expf(2.0f * x);
            float s4 = (1.0f - 2.0f / (e + 1.0f)) * v_col;
            s4 = wave_sum64(s4);                   // lane 63 = total
            if (ln == 63)
              __hip_atomic_store(&eb[(size_t)((t + 1) & 1) * 64 + 32 + g],
                  (unsigned long long)__float_as_uint(s4) |
                      ((unsigned long long)(t + 2) << 32),
                  __ATOMIC_RELAXED, __HIP_MEMORY_SCOPE_AGENT);
            s4_prev = __shfl(s4, 63, 64);          // off-critical broadcast
          }
          btB = bt2;
        }
        h_cur = h_nxt;
      }
    }
  }
}

extern "C" void kernel_launch(void* const* d_in, const int* in_sizes, int n_in,
                              void* d_out, int out_size, void* d_ws, size_t ws_size,
                              hipStream_t stream) {
  const float* H  = (const float*)d_in[0];
  const float* v  = (const float*)d_in[1];
  const float* W1 = (const float*)d_in[2];
  const float* W2 = (const float*)d_in[3];
  const float* W3 = (const float*)d_in[4];
  float* out = (float*)d_out;

  if (ws_size < WS_NEED) return;

  float* A = (float*)d_ws;
  unsigned long long* exch = (unsigned long long*)((char*)d_ws + EXCH_OFF);

  (void)hipMemsetAsync(exch, 0, EXCH_BYTES, stream);
  hipLaunchKernelGGL(th_phase1, dim3(256 * 8), dim3(256), 0, stream,
                     H, W1, W2, A, out);
  hipLaunchKernelGGL(th_phase2, dim3(BB * 8), dim3(512), 0, stream,
                     H, v, W3, A, out, exch);
}

// Round 16
// 977.718 us; speedup vs baseline: 23.0040x; 1.1359x over previous
//
#include <hip/hip_runtime.h>

// TruncatedHistoryAttn, round 22 = round 15/21 loop + bf16-MFMA PROLOGUE
// replacing phase1 (single kernel).
// Round-21 analysis: phase2 (857us) is at its sync-latency floor, but total
// 1110 carries ~250us of phase1 (fp32 GEMM @ 157TF vector ALU) + launches.
// Each WG consumes A/B2 only at its own 64-col slice -> each WG computes
// A[:,slice]=H_b@W1[:,slice] and B2[:,slice]=H_b@W2[:,slice] itself with
// bf16 MFMA (16x16x32): per wave 4mt x 4nt x 16k x 2 mats = 512 MFMA, a few
// us. A -> ws (self-read), B2 -> d_out (own-slice reads; all cross-WG
// orderings identical to round 15's proven ones). bf16 input error ~0.004 in
// x, squeezed by tanh*v/softmax -> absmax well under the 0.64 threshold.
// NEW hazard handled: g==0's t=0 tilde write to row 0 raced sibling prologue
// B2 writes (no poll at t=0) -> row-0 store deferred to step 1 (poll(1)
// proves siblings past prologue). Registers: prologue peak ~100 (64 acc,
// phase-local, disjoint from loop's 84) - unlike r16-r20's 192 persistent.
// MFMA layouts (cdna4_isa/guide, C/D HW-verified): A row=l&15 k=(l>>4)*8+i;
// B col=l&15 k=(l>>4)*8+i; D col=l&15 row=(l>>4)*4+i.
// Loop unchanged from round 15: tagged 8B agent words, early distributed
// publish, wave-0-only poll w/ self-j4 substitute, DPP sums, wave-local
// ds_read_b128 matvec, 2 barriers/step, grid 256.

#define BB 32
#define SS 512
#define DD 512
#define NS 5

#define A_ELEMS    ((size_t)BB * SS * DD)            // 32 MB
#define EXCH_U64_PER_B 128                           // 2 slots x 64 (40 used)
#define EXCH_OFF   (A_ELEMS * 4)
#define EXCH_BYTES ((size_t)BB * EXCH_U64_PER_B * 8) // 32 KB
#define WS_NEED    (EXCH_OFF + EXCH_BYTES)

typedef __attribute__((ext_vector_type(4))) float f32x4;
typedef __attribute__((ext_vector_type(8))) __bf16 bf16x8;

// ---- DPP cross-lane sum (rocPRIM sequence); ctrl words are template consts.
template <int CTRL, int RMASK, int BMASK, bool BC>
__device__ __forceinline__ float dpp_term(float x) {
  return __uint_as_float((unsigned)__builtin_amdgcn_update_dpp(
      0, (int)__float_as_uint(x), CTRL, RMASK, BMASK, BC));
}
__device__ __forceinline__ float wave_sum64(float x) {
  x += dpp_term<0xB1, 0xF, 0xF, true>(x);   // quad_perm [1,0,3,2] (xor 1)
  x += dpp_term<0x4E, 0xF, 0xF, true>(x);   // quad_perm [2,3,0,1] (xor 2)
  x += dpp_term<0x141, 0xF, 0xF, true>(x);  // row_half_mirror     (xor 4)
  x += dpp_term<0x140, 0xF, 0xF, true>(x);  // row_mirror          (xor 8)
  x += dpp_term<0x142, 0xA, 0xF, false>(x); // row_bcast15 -> rows 1,3
  x += dpp_term<0x143, 0xC, 0xF, false>(x); // row_bcast31 -> rows 2,3
  return x;                                 // lane 63: sum of all 64
}
__device__ __forceinline__ float group8_sum(float x) {
  x += dpp_term<0xB1, 0xF, 0xF, true>(x);
  x += dpp_term<0x4E, 0xF, 0xF, true>(x);
  x += dpp_term<0x141, 0xF, 0xF, true>(x);
  return x;
}

// grid 256 = 8 WGs/batch; bid = g*32+b.
__global__ void __launch_bounds__(512) th_phase2(
    const float* __restrict__ H, const float* __restrict__ v,
    const float* __restrict__ W1, const float* __restrict__ W2,
    const float* __restrict__ W3,
    float* __restrict__ A,             // ws: A = H@W1 (self-computed)
    float* __restrict__ Ob,            // d_out: B2 then tilde rows
    unsigned long long* __restrict__ exch) {
  const int tid = threadIdx.x;
  const int b = blockIdx.x & 31;
  const int g = blockIdx.x >> 5;     // 0..7: cols [g*64, g*64+64)
  const int q = tid >> 6;            // wave id == k-segment 0..7
  const int ln = tid & 63;
  const int col = (g << 6) + ln;

  __shared__ float tlds[DD];         // tilde_t row
  __shared__ float pm[DD];           // matvec k-segment partials
  __shared__ float wl[8];            // softmax weights broadcast

  const float* Hb = H + (size_t)b * SS * DD;
  float* Ab = A + (size_t)b * SS * DD;
  float* Op = Ob + (size_t)b * SS * DD;
  unsigned long long* eb = exch + (size_t)b * EXCH_U64_PER_B;

  // ================= PROLOGUE: A[:,gslice], B2[:,gslice] via bf16 MFMA ====
  {
    const int lm = ln & 15;            // row-in-tile (A) / col-in-tile (B,D)
    const int lkb = (ln >> 4) << 3;    // k-offset base: 0,8,16,24
    const int lr4 = (ln >> 4) << 2;    // D-row base: 0,4,8,12
#pragma unroll 1
    for (int mat = 0; mat < 2; ++mat) {
      const float* Wm = mat ? W2 : W1;
      float* Out = mat ? Op : Ab;
      f32x4 acc[4][4];
#pragma unroll
      for (int x = 0; x < 4; ++x)
#pragma unroll
        for (int y = 0; y < 4; ++y)
          acc[x][y] = (f32x4){0.f, 0.f, 0.f, 0.f};
#pragma unroll 1
      for (int s = 0; s < 16; ++s) {
        const int kb = s * 32 + lkb;
        bf16x8 af[4];
#pragma unroll
        for (int mt = 0; mt < 4; ++mt) {
          const float* hp = Hb + (size_t)(q * 64 + mt * 16 + lm) * DD + kb;
          float4 u0 = *(const float4*)hp;
          float4 u1 = *(const float4*)(hp + 4);
          bf16x8 t;
          t[0] = (__bf16)u0.x; t[1] = (__bf16)u0.y;
          t[2] = (__bf16)u0.z; t[3] = (__bf16)u0.w;
          t[4] = (__bf16)u1.x; t[5] = (__bf16)u1.y;
          t[6] = (__bf16)u1.z; t[7] = (__bf16)u1.w;
          af[mt] = t;
        }
#pragma unroll
        for (int nt = 0; nt < 4; ++nt) {
          const float* wp = Wm + (size_t)kb * DD + (g * 64 + nt * 16 + lm);
          bf16x8 bfr;
#pragma unroll
          for (int i = 0; i < 8; ++i) bfr[i] = (__bf16)wp[(size_t)i * DD];
#pragma unroll
          for (int mt = 0; mt < 4; ++mt)
            acc[mt][nt] = __builtin_amdgcn_mfma_f32_16x16x32_bf16(
                af[mt], bfr, acc[mt][nt], 0, 0, 0);
        }
      }
#pragma unroll
      for (int mt = 0; mt < 4; ++mt)
#pragma unroll
        for (int nt = 0; nt < 4; ++nt)
#pragma unroll
          for (int i = 0; i < 4; ++i)
            Out[(size_t)(q * 64 + mt * 16 + lr4 + i) * DD +
                (g * 64 + nt * 16 + lm)] = acc[mt][nt][i];
    }
    __syncthreads();                 // A/B2 slices visible WG-wide
  }

  // ================= recurrence (round-15 loop, row-0 write deferred) =====
  // W3 slice in plain VGPRs: wa[i] = W3[q*64+i][col]
  float wa[64];
#pragma unroll
  for (int i = 0; i < 64; ++i)
    wa[i] = W3[(size_t)(q * 64 + i) * DD + col];

  // waves 0..4: replica rings over this WG's 64 cols (row s in slot s%5)
  float v_col = (q < NS) ? v[col] : 0.f;
  float aA[NS] = {0.f, 0.f, 0.f, 0.f, 0.f};
  float cC[NS] = {0.f, 0.f, 0.f, 0.f, 0.f};
  float tl[NS] = {0.f, 0.f, 0.f, 0.f, 0.f};
  float s4_prev = 0.f;               // wave 0: own j=4 score (all lanes)
  float tld0 = 0.f;                  // deferred tilde row 0
  float h_cur = Hb[tid];
  float btB = (q < NS) ? Op[DD + col] : 0.f;  // B2 row 1 (own slice)

  if (tid < NS) wl[tid] = 0.2f;      // step-0 weights: exactly uniform

#pragma unroll 1
  for (int t5 = 0; t5 < 515; t5 += 5) {
#pragma unroll
    for (int p = 0; p < NS; ++p) {
      const int t = t5 + p;
      if (t < SS) {
        const bool pub = (t + 1 < SS);

        // ---- prefetches
        float aN_v = 0.f, bt2 = 0.f;
        if (q < NS) {
          aN_v = Ab[(size_t)t * DD + col];                  // A row t
          if (t + 2 < SS) bt2 = Op[(size_t)(t + 2) * DD + col];  // B2 row t+2
        }
        float h_nxt = 0.f;
        if (pub) h_nxt = Hb[(size_t)(t + 1) * DD + tid];

        // ---- waves 1..4: EARLY publish of score j=q-1 for step t+1
        if (q >= 1 && q < NS && pub) {
          float aa = aA[(p + 1) % NS];
          aa = (q == 2) ? aA[(p + 2) % NS] : aa;
          aa = (q == 3) ? aA[(p + 3) % NS] : aa;
          aa = (q == 4) ? aA[(p + 4) % NS] : aa;
          float cc = cC[(p + 1) % NS];
          cc = (q == 2) ? cC[(p + 2) % NS] : cc;
          cc = (q == 3) ? cC[(p + 3) % NS] : cc;
          cc = (q == 4) ? cC[(p + 4) % NS] : cc;
          float x = aa + btB + cc;
          float e = __expf(2.0f * x);
          float s = (1.0f - 2.0f / (e + 1.0f)) * v_col;
          s = wave_sum64(s);                       // lane 63 = total
          if (ln == 63)
            __hip_atomic_store(&eb[(size_t)((t + 1) & 1) * 64 + (q - 1) * 8 + g],
                (unsigned long long)__float_as_uint(s) |
                    ((unsigned long long)(t + 2) << 32),
                __ATOMIC_RELAXED, __HIP_MEMORY_SCOPE_AGENT);
        }

        // ---- wave 0: poll tagged words (slot t&1, tag t+1) -> softmax -> wl
        if (q == 0 && t >= 1) {
          const unsigned long long* wsl = eb + (size_t)(t & 1) * 64;
          float pv = 0.f;
          if (ln < 40) {
            if (!((ln >> 3) == 4 && (ln & 7) == g)) {
              unsigned long long w;
              do {
                w = __hip_atomic_load(&wsl[ln], __ATOMIC_RELAXED,
                                      __HIP_MEMORY_SCOPE_AGENT);
              } while ((unsigned)(w >> 32) != (unsigned)(t + 1));
              pv = __uint_as_float((unsigned)w);
            } else {
              pv = s4_prev;
            }
          }
          pv = group8_sum(pv);             // each 8-group holds its j-total
          float sc0 = __shfl(pv, 0, 64);
          float sc1 = __shfl(pv, 8, 64);
          float sc2 = __shfl(pv, 16, 64);
          float sc3 = __shfl(pv, 24, 64);
          float sc4 = __shfl(pv, 32, 64);
          float mx = fmaxf(fmaxf(fmaxf(sc0, sc1), fmaxf(sc2, sc3)), sc4);
          float e0 = __expf(sc0 - mx), e1 = __expf(sc1 - mx);
          float e2 = __expf(sc2 - mx), e3 = __expf(sc3 - mx);
          float e4 = __expf(sc4 - mx);
          float inv = 1.0f / (e0 + e1 + e2 + e3 + e4);
          float wv = e0 * inv;
          wv = (ln == 1) ? e1 * inv : wv;
          wv = (ln == 2) ? e2 * inv : wv;
          wv = (ln == 3) ? e3 * inv : wv;
          wv = (ln == 4) ? e4 * inv : wv;
          if (ln < NS) wl[ln] = wv;
        }
        __syncthreads();                           // A: weights ready

        // ---- all threads: tilde row (registers + 5 broadcast LDS reads)
        float w0 = wl[0], w1 = wl[1], w2 = wl[2], w3_ = wl[3], w4 = wl[4];
        float hh = w0 * tl[p];
        hh = fmaf(w1, tl[(p + 1) % NS], hh);
        hh = fmaf(w2, tl[(p + 2) % NS], hh);
        hh = fmaf(w3_, tl[(p + 3) % NS], hh);
        hh = fmaf(w4, tl[(p + 4) % NS], hh);
        float tld = h_cur + fmaxf(hh, 0.f);
        tl[p] = tld;
        tlds[tid] = tld;
        // row-t output: deferred for t=0 (no poll at t=0 -> could race
        // sibling prologue B2 writes); flushed at t=1 after poll(1).
        if (g == 0) {
          if (t == 0) {
            tld0 = tld;
          } else {
            Op[(size_t)t * DD + tid] = tld;
            if (t == 1) Op[tid] = tld0;
          }
        }
        // wave-local: matvec reads ONLY this wave's own tlds segment
        asm volatile("s_waitcnt lgkmcnt(0)" ::: "memory");

        // ---- matvec: own 64 cols, k in [q*64, q*64+64), wave-uniform reads
        float a0 = 0.f, a1 = 0.f, a2 = 0.f, a3 = 0.f;
        const f32x4* tv = (const f32x4*)&tlds[q << 6];
#pragma unroll
        for (int i = 0; i < 16; ++i) {
          f32x4 t4 = tv[i];
          a0 = fmaf(t4.x, wa[4 * i + 0], a0);
          a1 = fmaf(t4.y, wa[4 * i + 1], a1);
          a2 = fmaf(t4.z, wa[4 * i + 2], a2);
          a3 = fmaf(t4.w, wa[4 * i + 3], a3);
        }
        pm[tid] = (a0 + a1) + (a2 + a3);
        __syncthreads();                           // C: pm ready

        // ---- waves 0..4: k-reduce + ring update; wave 0: score j=4, publish
        if (q < NS) {
          float c = 0.f;
#pragma unroll
          for (int s = 0; s < 8; ++s) c += pm[s * 64 + ln];
          aA[p] = aN_v;                            // A row t -> slot t%5
          cC[p] = c;                               // c row t -> slot t%5
          if (q == 0 && pub) {
            float x = aN_v + btB + c;              // row t, bt = row t+1
            float e = __expf(2.0f * x);
            float s4 = (1.0f - 2.0f / (e + 1.0f)) * v_col;
            s4 = wave_sum64(s4);                   // lane 63 = total
            if (ln == 63)
              __hip_atomic_store(&eb[(size_t)((t + 1) & 1) * 64 + 32 + g],
                  (unsigned long long)__float_as_uint(s4) |
                      ((unsigned long long)(t + 2) << 32),
                  __ATOMIC_RELAXED, __HIP_MEMORY_SCOPE_AGENT);
            s4_prev = __shfl(s4, 63, 64);          // off-critical broadcast
          }
          btB = bt2;
        }
        h_cur = h_nxt;
      }
    }
  }
}

extern "C" void kernel_launch(void* const* d_in, const int* in_sizes, int n_in,
                              void* d_out, int out_size, void* d_ws, size_t ws_size,
                              hipStream_t stream) {
  const float* H  = (const float*)d_in[0];
  const float* v  = (const float*)d_in[1];
  const float* W1 = (const float*)d_in[2];
  const float* W2 = (const float*)d_in[3];
  const float* W3 = (const float*)d_in[4];
  float* out = (float*)d_out;

  if (ws_size < WS_NEED) return;

  float* A = (float*)d_ws;
  unsigned long long* exch = (unsigned long long*)((char*)d_ws + EXCH_OFF);

  (void)hipMemsetAsync(exch, 0, EXCH_BYTES, stream);
  hipLaunchKernelGGL(th_phase2, dim3(BB * 8), dim3(512), 0, stream,
                     H, v, W1, W2, W3, A, out, exch);
}

// Round 17
// 925.838 us; speedup vs baseline: 24.2930x; 1.0560x over previous
//
#include <hip/hip_runtime.h>

// TruncatedHistoryAttn, round 23 = round 22 + LDS-RESIDENT A/B2 (bf16).
// Round-22 post-mortem: merged prologue works (977us total) but materializes
// A+B2 to HBM (WRITE 53->119MB, FETCH 57->103MB: 64MB written + 64MB
// re-read + scattered global stores). Both slices are consumed ONLY by the
// producing WG (own-col reads) -> keep them in LDS as bf16:
//  - dynamic LDS: aS[512][64] + bS[512][64] bf16 = 128 KB (+4.6 KB static =
//    132.6 < 160 KB; grid is 1 WG/CU already, no occupancy change).
//  - prologue MFMA accs -> ds_write_b16; loop aN_v/bt2 = LDS reads.
//  - d_out now holds ONLY tilde rows (no reader) -> round-22's t=0 deferral
//    race is structurally gone; ws holds only the exchange.
//  - precision: bf16 A/B2 adds ~0.004 to x pre-tanh; squeezed by v/softmax,
//    well under the 0.64 threshold (current margin 5x at 0.125).
// Loop unchanged from round 15: tagged 8B agent words, early distributed
// publish, wave-0-only poll w/ self-j4 substitute, DPP sums, wave-local
// ds_read_b128 matvec, 2 barriers/step, grid 256.

#define BB 32
#define SS 512
#define DD 512
#define NS 5

#define EXCH_U64_PER_B 128                           // 2 slots x 64 (40 used)
#define EXCH_BYTES ((size_t)BB * EXCH_U64_PER_B * 8) // 32 KB
#define WS_NEED    EXCH_BYTES
#define DYN_LDS_BYTES ((size_t)2 * SS * 64 * 2)      // 128 KB (aS + bS)

typedef __attribute__((ext_vector_type(4))) float f32x4;
typedef __attribute__((ext_vector_type(8))) __bf16 bf16x8;

// ---- DPP cross-lane sum (rocPRIM sequence); ctrl words are template consts.
template <int CTRL, int RMASK, int BMASK, bool BC>
__device__ __forceinline__ float dpp_term(float x) {
  return __uint_as_float((unsigned)__builtin_amdgcn_update_dpp(
      0, (int)__float_as_uint(x), CTRL, RMASK, BMASK, BC));
}
__device__ __forceinline__ float wave_sum64(float x) {
  x += dpp_term<0xB1, 0xF, 0xF, true>(x);   // quad_perm [1,0,3,2] (xor 1)
  x += dpp_term<0x4E, 0xF, 0xF, true>(x);   // quad_perm [2,3,0,1] (xor 2)
  x += dpp_term<0x141, 0xF, 0xF, true>(x);  // row_half_mirror     (xor 4)
  x += dpp_term<0x140, 0xF, 0xF, true>(x);  // row_mirror          (xor 8)
  x += dpp_term<0x142, 0xA, 0xF, false>(x); // row_bcast15 -> rows 1,3
  x += dpp_term<0x143, 0xC, 0xF, false>(x); // row_bcast31 -> rows 2,3
  return x;                                 // lane 63: sum of all 64
}
__device__ __forceinline__ float group8_sum(float x) {
  x += dpp_term<0xB1, 0xF, 0xF, true>(x);
  x += dpp_term<0x4E, 0xF, 0xF, true>(x);
  x += dpp_term<0x141, 0xF, 0xF, true>(x);
  return x;
}

// grid 256 = 8 WGs/batch; bid = g*32+b.
__global__ void __launch_bounds__(512) th_fused(
    const float* __restrict__ H, const float* __restrict__ v,
    const float* __restrict__ W1, const float* __restrict__ W2,
    const float* __restrict__ W3,
    float* __restrict__ Ob,            // d_out: tilde rows only
    unsigned long long* __restrict__ exch) {
  const int tid = threadIdx.x;
  const int b = blockIdx.x & 31;
  const int g = blockIdx.x >> 5;     // 0..7: cols [g*64, g*64+64)
  const int q = tid >> 6;            // wave id == k-segment 0..7
  const int ln = tid & 63;
  const int col = (g << 6) + ln;

  __shared__ float tlds[DD];         // tilde_t row
  __shared__ float pm[DD];           // matvec k-segment partials
  __shared__ float wl[8];            // softmax weights broadcast
  extern __shared__ __align__(16) unsigned char dynls[];
  __bf16* aS = (__bf16*)dynls;               // [SS][64]: A slice (own cols)
  __bf16* bS = aS + (size_t)SS * 64;         // [SS][64]: B2 slice (own cols)

  const float* Hb = H + (size_t)b * SS * DD;
  float* Op = Ob + (size_t)b * SS * DD;
  unsigned long long* eb = exch + (size_t)b * EXCH_U64_PER_B;

  // ================= PROLOGUE: A/B2 slices via bf16 MFMA -> LDS ===========
  {
    const int lm = ln & 15;            // row-in-tile (A) / col-in-tile (B,D)
    const int lkb = (ln >> 4) << 3;    // k-offset base: 0,8,16,24
    const int lr4 = (ln >> 4) << 2;    // D-row base: 0,4,8,12
#pragma unroll 1
    for (int mat = 0; mat < 2; ++mat) {
      const float* Wm = mat ? W2 : W1;
      __bf16* Out = mat ? bS : aS;
      f32x4 acc[4][4];
#pragma unroll
      for (int x = 0; x < 4; ++x)
#pragma unroll
        for (int y = 0; y < 4; ++y)
          acc[x][y] = (f32x4){0.f, 0.f, 0.f, 0.f};
#pragma unroll 1
      for (int s = 0; s < 16; ++s) {
        const int kb = s * 32 + lkb;
        bf16x8 af[4];
#pragma unroll
        for (int mt = 0; mt < 4; ++mt) {
          const float* hp = Hb + (size_t)(q * 64 + mt * 16 + lm) * DD + kb;
          float4 u0 = *(const float4*)hp;
          float4 u1 = *(const float4*)(hp + 4);
          bf16x8 t;
          t[0] = (__bf16)u0.x; t[1] = (__bf16)u0.y;
          t[2] = (__bf16)u0.z; t[3] = (__bf16)u0.w;
          t[4] = (__bf16)u1.x; t[5] = (__bf16)u1.y;
          t[6] = (__bf16)u1.z; t[7] = (__bf16)u1.w;
          af[mt] = t;
        }
#pragma unroll
        for (int nt = 0; nt < 4; ++nt) {
          const float* wp = Wm + (size_t)kb * DD + (g * 64 + nt * 16 + lm);
          bf16x8 bfr;
#pragma unroll
          for (int i = 0; i < 8; ++i) bfr[i] = (__bf16)wp[(size_t)i * DD];
#pragma unroll
          for (int mt = 0; mt < 4; ++mt)
            acc[mt][nt] = __builtin_amdgcn_mfma_f32_16x16x32_bf16(
                af[mt], bfr, acc[mt][nt], 0, 0, 0);
        }
      }
#pragma unroll
      for (int mt = 0; mt < 4; ++mt)
#pragma unroll
        for (int nt = 0; nt < 4; ++nt)
#pragma unroll
          for (int i = 0; i < 4; ++i)
            Out[(size_t)(q * 64 + mt * 16 + lr4 + i) * 64 + nt * 16 + lm] =
                (__bf16)acc[mt][nt][i];
    }
    __syncthreads();                 // A/B2 slices visible WG-wide
  }

  // ================= recurrence (round-15 loop, A/B2 from LDS) ============
  // W3 slice in plain VGPRs: wa[i] = W3[q*64+i][col]
  float wa[64];
#pragma unroll
  for (int i = 0; i < 64; ++i)
    wa[i] = W3[(size_t)(q * 64 + i) * DD + col];

  // waves 0..4: replica rings over this WG's 64 cols (row s in slot s%5)
  float v_col = (q < NS) ? v[col] : 0.f;
  float aA[NS] = {0.f, 0.f, 0.f, 0.f, 0.f};
  float cC[NS] = {0.f, 0.f, 0.f, 0.f, 0.f};
  float tl[NS] = {0.f, 0.f, 0.f, 0.f, 0.f};
  float s4_prev = 0.f;               // wave 0: own j=4 score (all lanes)
  float h_cur = Hb[tid];
  float btB = (q < NS) ? (float)bS[64 + ln] : 0.f;  // B2 row 1 (own col)

  if (tid < NS) wl[tid] = 0.2f;      // step-0 weights: exactly uniform

#pragma unroll 1
  for (int t5 = 0; t5 < 515; t5 += 5) {
#pragma unroll
    for (int p = 0; p < NS; ++p) {
      const int t = t5 + p;
      if (t < SS) {
        const bool pub = (t + 1 < SS);

        // ---- prefetches (A row t, B2 row t+2 from LDS; H row t+1 global)
        float aN_v = 0.f, bt2 = 0.f;
        if (q < NS) {
          aN_v = (float)aS[(size_t)t * 64 + ln];
          if (t + 2 < SS) bt2 = (float)bS[(size_t)(t + 2) * 64 + ln];
        }
        float h_nxt = 0.f;
        if (pub) h_nxt = Hb[(size_t)(t + 1) * DD + tid];

        // ---- waves 1..4: EARLY publish of score j=q-1 for step t+1
        if (q >= 1 && q < NS && pub) {
          float aa = aA[(p + 1) % NS];
          aa = (q == 2) ? aA[(p + 2) % NS] : aa;
          aa = (q == 3) ? aA[(p + 3) % NS] : aa;
          aa = (q == 4) ? aA[(p + 4) % NS] : aa;
          float cc = cC[(p + 1) % NS];
          cc = (q == 2) ? cC[(p + 2) % NS] : cc;
          cc = (q == 3) ? cC[(p + 3) % NS] : cc;
          cc = (q == 4) ? cC[(p + 4) % NS] : cc;
          float x = aa + btB + cc;
          float e = __expf(2.0f * x);
          float s = (1.0f - 2.0f / (e + 1.0f)) * v_col;
          s = wave_sum64(s);                       // lane 63 = total
          if (ln == 63)
            __hip_atomic_store(&eb[(size_t)((t + 1) & 1) * 64 + (q - 1) * 8 + g],
                (unsigned long long)__float_as_uint(s) |
                    ((unsigned long long)(t + 2) << 32),
                __ATOMIC_RELAXED, __HIP_MEMORY_SCOPE_AGENT);
        }

        // ---- wave 0: poll tagged words (slot t&1, tag t+1) -> softmax -> wl
        if (q == 0 && t >= 1) {
          const unsigned long long* wsl = eb + (size_t)(t & 1) * 64;
          float pv = 0.f;
          if (ln < 40) {
            if (!((ln >> 3) == 4 && (ln & 7) == g)) {
              unsigned long long w;
              do {
                w = __hip_atomic_load(&wsl[ln], __ATOMIC_RELAXED,
                                      __HIP_MEMORY_SCOPE_AGENT);
              } while ((unsigned)(w >> 32) != (unsigned)(t + 1));
              pv = __uint_as_float((unsigned)w);
            } else {
              pv = s4_prev;
            }
          }
          pv = group8_sum(pv);             // each 8-group holds its j-total
          float sc0 = __shfl(pv, 0, 64);
          float sc1 = __shfl(pv, 8, 64);
          float sc2 = __shfl(pv, 16, 64);
          float sc3 = __shfl(pv, 24, 64);
          float sc4 = __shfl(pv, 32, 64);
          float mx = fmaxf(fmaxf(fmaxf(sc0, sc1), fmaxf(sc2, sc3)), sc4);
          float e0 = __expf(sc0 - mx), e1 = __expf(sc1 - mx);
          float e2 = __expf(sc2 - mx), e3 = __expf(sc3 - mx);
          float e4 = __expf(sc4 - mx);
          float inv = 1.0f / (e0 + e1 + e2 + e3 + e4);
          float wv = e0 * inv;
          wv = (ln == 1) ? e1 * inv : wv;
          wv = (ln == 2) ? e2 * inv : wv;
          wv = (ln == 3) ? e3 * inv : wv;
          wv = (ln == 4) ? e4 * inv : wv;
          if (ln < NS) wl[ln] = wv;
        }
        __syncthreads();                           // A: weights ready

        // ---- all threads: tilde row (registers + 5 broadcast LDS reads)
        float w0 = wl[0], w1 = wl[1], w2 = wl[2], w3_ = wl[3], w4 = wl[4];
        float hh = w0 * tl[p];
        hh = fmaf(w1, tl[(p + 1) % NS], hh);
        hh = fmaf(w2, tl[(p + 2) % NS], hh);
        hh = fmaf(w3_, tl[(p + 3) % NS], hh);
        hh = fmaf(w4, tl[(p + 4) % NS], hh);
        float tld = h_cur + fmaxf(hh, 0.f);
        tl[p] = tld;
        tlds[tid] = tld;
        if (g == 0) Op[(size_t)t * DD + tid] = tld;  // output row t (no reader)
        // wave-local: matvec reads ONLY this wave's own tlds segment
        asm volatile("s_waitcnt lgkmcnt(0)" ::: "memory");

        // ---- matvec: own 64 cols, k in [q*64, q*64+64), wave-uniform reads
        float a0 = 0.f, a1 = 0.f, a2 = 0.f, a3 = 0.f;
        const f32x4* tv = (const f32x4*)&tlds[q << 6];
#pragma unroll
        for (int i = 0; i < 16; ++i) {
          f32x4 t4 = tv[i];
          a0 = fmaf(t4.x, wa[4 * i + 0], a0);
          a1 = fmaf(t4.y, wa[4 * i + 1], a1);
          a2 = fmaf(t4.z, wa[4 * i + 2], a2);
          a3 = fmaf(t4.w, wa[4 * i + 3], a3);
        }
        pm[tid] = (a0 + a1) + (a2 + a3);
        __syncthreads();                           // C: pm ready

        // ---- waves 0..4: k-reduce + ring update; wave 0: score j=4, publish
        if (q < NS) {
          float c = 0.f;
#pragma unroll
          for (int s = 0; s < 8; ++s) c += pm[s * 64 + ln];
          aA[p] = aN_v;                            // A row t -> slot t%5
          cC[p] = c;                               // c row t -> slot t%5
          if (q == 0 && pub) {
            float x = aN_v + btB + c;              // row t, bt = row t+1
            float e = __expf(2.0f * x);
            float s4 = (1.0f - 2.0f / (e + 1.0f)) * v_col;
            s4 = wave_sum64(s4);                   // lane 63 = total
            if (ln == 63)
              __hip_atomic_store(&eb[(size_t)((t + 1) & 1) * 64 + 32 + g],
                  (unsigned long long)__float_as_uint(s4) |
                      ((unsigned long long)(t + 2) << 32),
                  __ATOMIC_RELAXED, __HIP_MEMORY_SCOPE_AGENT);
            s4_prev = __shfl(s4, 63, 64);          // off-critical broadcast
          }
          btB = bt2;
        }
        h_cur = h_nxt;
      }
    }
  }
}

extern "C" void kernel_launch(void* const* d_in, const int* in_sizes, int n_in,
                              void* d_out, int out_size, void* d_ws, size_t ws_size,
                              hipStream_t stream) {
  const float* H  = (const float*)d_in[0];
  const float* v  = (const float*)d_in[1];
  const float* W1 = (const float*)d_in[2];
  const float* W2 = (const float*)d_in[3];
  const float* W3 = (const float*)d_in[4];
  float* out = (float*)d_out;

  if (ws_size < WS_NEED) return;

  unsigned long long* exch = (unsigned long long*)d_ws;

  (void)hipMemsetAsync(exch, 0, EXCH_BYTES, stream);
  hipLaunchKernelGGL(th_fused, dim3(BB * 8), dim3(512), DYN_LDS_BYTES, stream,
                     H, v, W1, W2, W3, out, exch);
}